// Round 1
// baseline (58.093 us; speedup 1.0000x reference)
//
#include <hip/hip_runtime.h>
#include <math.h>

#define M_GT 128
#define NLEV 5
#define KCAND 135   // 5 levels * 27
#define TOPK_LOC 9

__device__ __forceinline__ float waveReduceSumF(float v) {
    #pragma unroll
    for (int off = 32; off > 0; off >>= 1)
        v += __shfl_xor(v, off, 64);
    return v;
}

// One wave (64 threads) per (b, m) pair.
__global__ __launch_bounds__(64) void atss_assign_kernel(
    const float* __restrict__ ann,   // [B, 128, 3]
    const float* __restrict__ a0,
    const float* __restrict__ a1,
    const float* __restrict__ a2,
    const float* __restrict__ a3,
    const float* __restrict__ a4,
    unsigned char* __restrict__ pos, // [B, A]
    int A)
{
    const int Llev[NLEV] = {8192, 4096, 2048, 1024, 512};
    const float* aptr[NLEV] = {a0, a1, a2, a3, a4};
    int base[NLEV];
    base[0] = 0;
    #pragma unroll
    for (int l = 1; l < NLEV; ++l) base[l] = base[l-1] + 3*Llev[l-1];

    int pair = blockIdx.x;
    int b = pair >> 7, m = pair & 127;
    const float* g = ann + ((size_t)b*M_GT + m)*3;
    float gs = g[0], ge = g[1];
    float gc = (gs + ge)*0.5f;
    float glen = ge - gs;

    // Per level: contiguous window of the 9 nearest locations.
    // Centers c_j=(j+0.5)*s are exact f32 (s is a power of two), distances on
    // one side strictly ordered, cross-side tie -> lower index (matches top_k).
    int lo_arr[NLEV];
    #pragma unroll
    for (int l = 0; l < NLEV; ++l) {
        int L = Llev[l];
        float s = 65536.0f / (float)L;
        int j0 = (int)floorf(gc / s);
        if (j0 < 0) j0 = 0;
        if (j0 > L-1) j0 = L-1;
        int best = j0;
        float bd = fabsf(((float)j0 + 0.5f)*s - gc);
        if (j0 > 0) {
            float d = fabsf(((float)j0 - 0.5f)*s - gc);
            if (d <= bd) { best = j0-1; bd = d; }   // tie -> lower index
        }
        if (j0+1 < L) {
            float d = fabsf(((float)j0 + 1.5f)*s - gc);
            if (d < bd)  { best = j0+1; bd = d; }   // strict: keep lower on tie
        }
        int lo = best, hi = best+1;
        #pragma unroll
        for (int t = 1; t < TOPK_LOC; ++t) {
            float dl = (lo > 0) ? fabsf(((float)(lo-1) + 0.5f)*s - gc) : 3.4e38f;
            float dr = (hi < L) ? fabsf(((float)hi    + 0.5f)*s - gc) : 3.4e38f;
            if (dl <= dr) --lo; else ++hi;          // tie -> left (lower index)
        }
        lo_arr[l] = lo;
    }

    int lane = threadIdx.x;
    float iouv[3], cxv[3];
    int gidx[3];
    float sum = 0.f;
    #pragma unroll
    for (int it = 0; it < 3; ++it) {
        int c = lane + it*64;
        gidx[it] = -1; iouv[it] = 0.f; cxv[it] = 0.f;
        if (c < KCAND) {
            int lev = c / 27;
            int w   = c % 27;
            int loc = lo_arr[lev] + w/3;
            int sc  = w % 3;
            int lidx = loc*3 + sc;
            const float* ap = aptr[lev] + (size_t)lidx*2;
            float as_ = ap[0], ae_ = ap[1];
            float iw = fminf(ae_, ge) - fmaxf(as_, gs);
            iw = fmaxf(iw, 0.f);
            float ua = (ae_ - as_) + glen - iw;
            ua = fmaxf(ua, 1e-8f);
            float iou = iw / ua;
            iouv[it] = iou;
            cxv[it]  = (as_ + ae_)*0.5f;
            gidx[it] = base[lev] + lidx;
            sum += iou;
        }
    }
    sum = waveReduceSumF(sum);
    float mean = sum / (float)KCAND;
    float s2 = 0.f;
    #pragma unroll
    for (int it = 0; it < 3; ++it)
        if (gidx[it] >= 0) { float d = iouv[it] - mean; s2 += d*d; }
    s2 = waveReduceSumF(s2);
    float thresh = mean + sqrtf(s2 / (float)(KCAND - 1));  // ddof=1

    unsigned char* posb = pos + (size_t)b*A;
    #pragma unroll
    for (int it = 0; it < 3; ++it) {
        if (gidx[it] >= 0 && iouv[it] >= thresh) {
            float l_ = cxv[it] - gs;
            float r_ = ge - cxv[it];
            if (fminf(l_, r_) > 0.01f) posb[gidx[it]] = 1;  // benign race: same value
        }
    }
}

__global__ __launch_bounds__(256) void focal_kernel(
    const float* __restrict__ cls,   // [B, A, C]
    const unsigned char* __restrict__ pos,
    const int* __restrict__ cidp,
    float* __restrict__ sums,        // [B]
    int* __restrict__ counts,        // [B]
    int A, int C)
{
    int b = blockIdx.y;
    int a = blockIdx.x*blockDim.x + threadIdx.x;
    int cid = *cidp;
    float local = 0.f;
    int myp = 0;
    if (a < A) {
        myp = pos[(size_t)b*A + a];
        const float* p = cls + ((size_t)b*A + a)*C;
        for (int c = 0; c < C; ++c) {
            float x = p[c];
            x = fminf(fmaxf(x, 1e-4f), 0.9999f);
            bool one = (myp != 0) && (c == cid);
            float t;
            if (one) { float q = 1.f - x; t = 0.25f * q*q * (-logf(x)); }
            else     {                     t = 0.75f * x*x * (-logf(1.f - x)); }
            local += t;
        }
    }
    __shared__ float sred[256];
    __shared__ int   cred[256];
    sred[threadIdx.x] = local;
    cred[threadIdx.x] = myp;
    __syncthreads();
    for (int s = 128; s > 0; s >>= 1) {
        if (threadIdx.x < s) {
            sred[threadIdx.x] += sred[threadIdx.x + s];
            cred[threadIdx.x] += cred[threadIdx.x + s];
        }
        __syncthreads();
    }
    if (threadIdx.x == 0) {
        atomicAdd(sums + b,  sred[0]);
        atomicAdd(counts + b, cred[0]);
    }
}

__global__ void finalize_kernel(const float* __restrict__ sums,
                                const int* __restrict__ counts,
                                float* __restrict__ out, int B)
{
    if (blockIdx.x == 0 && threadIdx.x == 0) {
        float acc = 0.f;
        for (int b = 0; b < B; ++b) {
            float np_ = fmaxf((float)counts[b], 1.0f);
            acc += sums[b] / np_;
        }
        out[0] = acc / (float)B;
    }
}

extern "C" void kernel_launch(void* const* d_in, const int* in_sizes, int n_in,
                              void* d_out, int out_size, void* d_ws, size_t ws_size,
                              hipStream_t stream)
{
    // setup_inputs() dict order: classifications, annotations, class_id, anchors_l0..l4
    // (be robust: class_id is the size-1 entry)
    const float* cls = (const float*)d_in[0];
    const float* ann = (const float*)d_in[1];
    const int* cid;
    const float *a0, *a1, *a2, *a3, *a4;
    int ai;
    if (in_sizes[2] == 1) { cid = (const int*)d_in[2]; ai = 3; }
    else                  { cid = (const int*)d_in[7]; ai = 2; }
    a0 = (const float*)d_in[ai+0];
    a1 = (const float*)d_in[ai+1];
    a2 = (const float*)d_in[ai+2];
    a3 = (const float*)d_in[ai+3];
    a4 = (const float*)d_in[ai+4];

    int A = (in_sizes[ai] + in_sizes[ai+1] + in_sizes[ai+2] + in_sizes[ai+3] + in_sizes[ai+4]) / 2;
    int B = in_sizes[1] / (M_GT * 3);
    int C = (int)((long long)in_sizes[0] / ((long long)B * A));

    unsigned char* pos = (unsigned char*)d_ws;
    size_t posBytes = (size_t)B * A;
    size_t aligned = (posBytes + 255) & ~(size_t)255;
    float* sums  = (float*)((char*)d_ws + aligned);
    int*   cnts  = (int*)  ((char*)d_ws + aligned + (size_t)B*sizeof(float));
    hipMemsetAsync(d_ws, 0, aligned + (size_t)B*(sizeof(float)+sizeof(int)), stream);

    atss_assign_kernel<<<B*M_GT, 64, 0, stream>>>(ann, a0, a1, a2, a3, a4, pos, A);

    dim3 g2((A + 255)/256, B);
    focal_kernel<<<g2, 256, 0, stream>>>(cls, pos, cid, sums, cnts, A, C);

    finalize_kernel<<<1, 64, 0, stream>>>(sums, cnts, (float*)d_out, B);
}

// Round 2
// 27.133 us; speedup vs baseline: 2.1411x; 2.1411x over previous
//
#include <hip/hip_runtime.h>
#include <math.h>

#define M_GT 128
#define NLEV 5
#define KCAND 135   // 5 levels * 27
#define TOPK_LOC 9

__device__ __forceinline__ float waveReduceSumF(float v) {
    #pragma unroll
    for (int off = 32; off > 0; off >>= 1)
        v += __shfl_xor(v, off, 64);
    return v;
}

// One wave (64 threads) per (b, m) pair.
__global__ __launch_bounds__(64) void atss_assign_kernel(
    const float* __restrict__ ann,   // [B, 128, 3]
    const float* __restrict__ a0,
    const float* __restrict__ a1,
    const float* __restrict__ a2,
    const float* __restrict__ a3,
    const float* __restrict__ a4,
    unsigned char* __restrict__ pos, // [B, A]
    int A)
{
    const int Llev[NLEV] = {8192, 4096, 2048, 1024, 512};
    const float* aptr[NLEV] = {a0, a1, a2, a3, a4};
    int base[NLEV];
    base[0] = 0;
    #pragma unroll
    for (int l = 1; l < NLEV; ++l) base[l] = base[l-1] + 3*Llev[l-1];

    int pair = blockIdx.x;
    int b = pair >> 7, m = pair & 127;
    const float* g = ann + ((size_t)b*M_GT + m)*3;
    float gs = g[0], ge = g[1];
    float gc = (gs + ge)*0.5f;
    float glen = ge - gs;

    // Per level: contiguous window of the 9 nearest locations.
    // Centers c_j=(j+0.5)*s are exact f32 (s is a power of two), distances on
    // one side strictly ordered, cross-side tie -> lower index (matches top_k).
    int lo_arr[NLEV];
    #pragma unroll
    for (int l = 0; l < NLEV; ++l) {
        int L = Llev[l];
        float s = 65536.0f / (float)L;
        int j0 = (int)floorf(gc / s);
        if (j0 < 0) j0 = 0;
        if (j0 > L-1) j0 = L-1;
        int best = j0;
        float bd = fabsf(((float)j0 + 0.5f)*s - gc);
        if (j0 > 0) {
            float d = fabsf(((float)j0 - 0.5f)*s - gc);
            if (d <= bd) { best = j0-1; bd = d; }   // tie -> lower index
        }
        if (j0+1 < L) {
            float d = fabsf(((float)j0 + 1.5f)*s - gc);
            if (d < bd)  { best = j0+1; bd = d; }   // strict: keep lower on tie
        }
        int lo = best, hi = best+1;
        #pragma unroll
        for (int t = 1; t < TOPK_LOC; ++t) {
            float dl = (lo > 0) ? fabsf(((float)(lo-1) + 0.5f)*s - gc) : 3.4e38f;
            float dr = (hi < L) ? fabsf(((float)hi    + 0.5f)*s - gc) : 3.4e38f;
            if (dl <= dr) --lo; else ++hi;          // tie -> left (lower index)
        }
        lo_arr[l] = lo;
    }

    int lane = threadIdx.x;
    float iouv[3], cxv[3];
    int gidx[3];
    float sum = 0.f;
    #pragma unroll
    for (int it = 0; it < 3; ++it) {
        int c = lane + it*64;
        gidx[it] = -1; iouv[it] = 0.f; cxv[it] = 0.f;
        if (c < KCAND) {
            int lev = c / 27;
            int w   = c % 27;
            int loc = lo_arr[lev] + w/3;
            int sc  = w % 3;
            int lidx = loc*3 + sc;
            const float* ap = aptr[lev] + (size_t)lidx*2;
            float as_ = ap[0], ae_ = ap[1];
            float iw = fminf(ae_, ge) - fmaxf(as_, gs);
            iw = fmaxf(iw, 0.f);
            float ua = (ae_ - as_) + glen - iw;
            ua = fmaxf(ua, 1e-8f);
            float iou = iw / ua;
            iouv[it] = iou;
            cxv[it]  = (as_ + ae_)*0.5f;
            gidx[it] = base[lev] + lidx;
            sum += iou;
        }
    }
    sum = waveReduceSumF(sum);
    float mean = sum / (float)KCAND;
    float s2 = 0.f;
    #pragma unroll
    for (int it = 0; it < 3; ++it)
        if (gidx[it] >= 0) { float d = iouv[it] - mean; s2 += d*d; }
    s2 = waveReduceSumF(s2);
    float thresh = mean + sqrtf(s2 / (float)(KCAND - 1));  // ddof=1

    unsigned char* posb = pos + (size_t)b*A;
    #pragma unroll
    for (int it = 0; it < 3; ++it) {
        if (gidx[it] >= 0 && iouv[it] >= thresh) {
            float l_ = cxv[it] - gs;
            float r_ = ge - cxv[it];
            if (fminf(l_, r_) > 0.01f) posb[gidx[it]] = 1;  // benign race: same value
        }
    }
}

// Per-block partial sums -> workspace. NO atomics (same-line atomic
// serialization was the 45 us fixed cost in R1).
__global__ __launch_bounds__(256) void focal_kernel(
    const float* __restrict__ cls,   // [B, A, C]
    const unsigned char* __restrict__ pos,
    const int* __restrict__ cidp,
    float* __restrict__ psums,       // [B, GX]
    int* __restrict__ pcnts,         // [B, GX]
    int A, int C, int GX)
{
    int b = blockIdx.y;
    int a = blockIdx.x*blockDim.x + threadIdx.x;
    int cid = *cidp;
    float local = 0.f;
    int myp = 0;
    if (a < A) {
        myp = pos[(size_t)b*A + a];
        const float* p = cls + ((size_t)b*A + a)*C;
        if (C == 8) {
            // vectorized fast path: 2x float4 per anchor (32B/lane)
            const float4* p4 = (const float4*)p;
            float4 u = p4[0], v = p4[1];
            float x8[8] = {u.x, u.y, u.z, u.w, v.x, v.y, v.z, v.w};
            #pragma unroll
            for (int c = 0; c < 8; ++c) {
                float x = fminf(fmaxf(x8[c], 1e-4f), 0.9999f);
                bool one = (myp != 0) && (c == cid);
                if (one) { float q = 1.f - x; local += 0.25f * q*q * (-__logf(x)); }
                else     {                     local += 0.75f * x*x * (-__logf(1.f - x)); }
            }
        } else {
            for (int c = 0; c < C; ++c) {
                float x = fminf(fmaxf(p[c], 1e-4f), 0.9999f);
                bool one = (myp != 0) && (c == cid);
                if (one) { float q = 1.f - x; local += 0.25f * q*q * (-__logf(x)); }
                else     {                     local += 0.75f * x*x * (-__logf(1.f - x)); }
            }
        }
    }
    // wave reduce, then cross-wave via LDS (4 waves)
    local = waveReduceSumF(local);
    float cf = waveReduceSumF((float)myp);
    __shared__ float sred[4];
    __shared__ float cred[4];
    int wid = threadIdx.x >> 6;
    if ((threadIdx.x & 63) == 0) { sred[wid] = local; cred[wid] = cf; }
    __syncthreads();
    if (threadIdx.x == 0) {
        float s = sred[0] + sred[1] + sred[2] + sred[3];
        float c = cred[0] + cred[1] + cred[2] + cred[3];
        psums[(size_t)b*GX + blockIdx.x] = s;
        pcnts[(size_t)b*GX + blockIdx.x] = (int)c;
    }
}

__global__ __launch_bounds__(64) void finalize_kernel(
    const float* __restrict__ psums,
    const int* __restrict__ pcnts,
    float* __restrict__ out, int B, int GX)
{
    int lane = threadIdx.x;
    float total = 0.f;
    for (int b = 0; b < B; ++b) {
        float s = 0.f, c = 0.f;
        for (int g = lane; g < GX; g += 64) {
            s += psums[(size_t)b*GX + g];
            c += (float)pcnts[(size_t)b*GX + g];
        }
        s = waveReduceSumF(s);
        c = waveReduceSumF(c);
        total += s / fmaxf(c, 1.0f);
    }
    if (lane == 0) out[0] = total / (float)B;
}

extern "C" void kernel_launch(void* const* d_in, const int* in_sizes, int n_in,
                              void* d_out, int out_size, void* d_ws, size_t ws_size,
                              hipStream_t stream)
{
    const float* cls = (const float*)d_in[0];
    const float* ann = (const float*)d_in[1];
    const int* cid;
    const float *a0, *a1, *a2, *a3, *a4;
    int ai;
    if (in_sizes[2] == 1) { cid = (const int*)d_in[2]; ai = 3; }
    else                  { cid = (const int*)d_in[7]; ai = 2; }
    a0 = (const float*)d_in[ai+0];
    a1 = (const float*)d_in[ai+1];
    a2 = (const float*)d_in[ai+2];
    a3 = (const float*)d_in[ai+3];
    a4 = (const float*)d_in[ai+4];

    int A = (in_sizes[ai] + in_sizes[ai+1] + in_sizes[ai+2] + in_sizes[ai+3] + in_sizes[ai+4]) / 2;
    int B = in_sizes[1] / (M_GT * 3);
    int C = (int)((long long)in_sizes[0] / ((long long)B * A));
    int GX = (A + 255) / 256;

    unsigned char* pos = (unsigned char*)d_ws;
    size_t posBytes = (size_t)B * A;
    size_t aligned = (posBytes + 255) & ~(size_t)255;
    float* psums = (float*)((char*)d_ws + aligned);
    int*   pcnts = (int*)  ((char*)d_ws + aligned + (size_t)B*GX*sizeof(float));

    // only the pos mask needs zeroing; partials are fully overwritten
    hipMemsetAsync(d_ws, 0, posBytes, stream);

    atss_assign_kernel<<<B*M_GT, 64, 0, stream>>>(ann, a0, a1, a2, a3, a4, pos, A);

    dim3 g2(GX, B);
    focal_kernel<<<g2, 256, 0, stream>>>(cls, pos, cid, psums, pcnts, A, C, GX);

    finalize_kernel<<<1, 64, 0, stream>>>(psums, pcnts, (float*)d_out, B, GX);
}